// Round 9
// baseline (93.169 us; speedup 1.0000x reference)
//
#include <hip/hip_runtime.h>
#include <stdint.h>

// Sizes fixed by the problem.
#define DM 1024   // D_MODEL
#define NN 2048   // NUM_NEURONS
#define BB 64     // batch (== wavefront size!)

static constexpr float INV2PI = 0.15915494309189535f;

__device__ __forceinline__ uint32_t bf16r(float x) {
  uint32_t b = __float_as_uint(x);
  b += 0x7fffu + ((b >> 16) & 1u);
  return b >> 16;
}

// ---------------- K0: prep ----------------
// blocks [0,32):   xcombP tiles (x_real/x_imag [64][1024] -> [1024 kpair][64 b] float2)
// blocks [32,288): rinv = 1/(1+|W|) elementwise (2M f32)
__global__ __launch_bounds__(256) void k0_prep(
    const float* __restrict__ xr, const float* __restrict__ xi,
    const float* __restrict__ W,
    float* __restrict__ xcombP, float* __restrict__ rinv)
{
  __shared__ float tile[64][65];
  int bid = blockIdx.x;
  int t = threadIdx.x;
  if (bid < 32) {
    int j = bid;  // k-tile of 64 over concatenated 2048
    int k0 = j * 64;
    const float* src = (k0 < 1024) ? xr : xi;
    int koff = k0 & 1023;
    int c = t & 63, rl = t >> 6;
#pragma unroll
    for (int i = 0; i < 16; ++i) {
      int b = rl * 16 + i;
      tile[b][c] = src[b * 1024 + koff + c];  // tile[b][k_local]
    }
    __syncthreads();
    float2* out2 = (float2*)xcombP;  // [1024 kpair][64 b]
    int bl = t & 63, kp = t >> 6;    // kp 0..3
#pragma unroll
    for (int i = 0; i < 8; ++i) {
      int kl = (kp * 8 + i) * 2;
      float2 v = make_float2(tile[bl][kl], tile[bl][kl + 1]);
      out2[(size_t)((k0 + kl) >> 1) * 64 + bl] = v;
    }
  } else {
    int j = bid - 32;  // 0..255, 2048 float4 each over 524288 total
    const float4* W4 = (const float4*)W;
    float4* R4 = (float4*)rinv;
    int base = j * 2048 + t;
#pragma unroll
    for (int i = 0; i < 8; ++i) {
      int idx = base + i * 256;
      float4 w = W4[idx];
      float4 r;
      r.x = 1.0f / (1.0f + fabsf(w.x));
      r.y = 1.0f / (1.0f + fabsf(w.y));
      r.z = 1.0f / (1.0f + fabsf(w.z));
      r.w = 1.0f / (1.0f + fabsf(w.w));
      R4[idx] = r;
    }
  }
}

// ---------------- K1: x_collapsed (d-tile 4, batched s_loads) --------------
// xc[b,d] = sum_k xcomb[b,k]*ic_w[d,k] + ic_b[d]; store packed bf16 pairs of
// xc*INV2PI as xcp[d/2][b]. 16 k-steps per batch: 4 rows x 64 B s_loads
// (dwordx16-mergeable) + 8 float2 x-loads hoisted upfront.
__global__ __launch_bounds__(512) void k1_collapse(
    const float* __restrict__ xcombP, const float* __restrict__ icw,
    const float* __restrict__ icb, uint32_t* __restrict__ xcp)
{
  __shared__ float part[8][4][64];
  int d0 = blockIdx.x * 4;
  int wave = __builtin_amdgcn_readfirstlane((int)(threadIdx.x >> 6));
  int lane = threadIdx.x & 63;
  const float2* P2 = (const float2*)xcombP;
  float acc[4] = {0.f, 0.f, 0.f, 0.f};
  int kbase = wave * 256;
  for (int kk = 0; kk < 256; kk += 16) {
    int k = kbase + kk;
    float4 w[4][4];
#pragma unroll
    for (int r = 0; r < 4; ++r)
#pragma unroll
      for (int j = 0; j < 4; ++j)
        w[r][j] = *(const float4*)(icw + (size_t)(d0 + r) * 2048 + k + 4 * j);
    float2 xv[8];
#pragma unroll
    for (int j = 0; j < 8; ++j)
      xv[j] = P2[(size_t)((k >> 1) + j) * 64 + lane];
#pragma unroll
    for (int j = 0; j < 4; ++j) {
#pragma unroll
      for (int r = 0; r < 4; ++r) {
        acc[r] = fmaf(w[r][j].x, xv[2 * j].x, acc[r]);
        acc[r] = fmaf(w[r][j].y, xv[2 * j].y, acc[r]);
        acc[r] = fmaf(w[r][j].z, xv[2 * j + 1].x, acc[r]);
        acc[r] = fmaf(w[r][j].w, xv[2 * j + 1].y, acc[r]);
      }
    }
  }
#pragma unroll
  for (int r = 0; r < 4; ++r) part[wave][r][lane] = acc[r];
  __syncthreads();
  int t = threadIdx.x;
  if (t < 128) {
    int pj = t >> 6;  // 0..1 (d-pair within tile)
    int b = t & 63;
    float s0 = 0.f, s1 = 0.f;
#pragma unroll
    for (int w = 0; w < 8; ++w) {
      s0 += part[w][2 * pj][b];
      s1 += part[w][2 * pj + 1][b];
    }
    float x0 = (s0 + icb[d0 + 2 * pj]) * INV2PI;
    float x1 = (s1 + icb[d0 + 2 * pj + 1]) * INV2PI;
    uint32_t u = bf16r(x0) | (bf16r(x1) << 16);
    xcp[(size_t)((d0 >> 1) + pj) * 64 + b] = u;
  }
}

// ---------------- K2: the resonant map-reduce (dominant; R6-proven) --------
// lane = b. wave owns (n, d-eighth q). LDS: xcp slice (16 KB) + params
// (16 KB), all staged before one barrier; inner loop pure LDS+VALU+trans.
// 8 accumulators for ILP.
#define K2_STEP(r4, b4, a4, s4, xu0, xu1, AC0, AS0, AC1, AS1)              \
  do {                                                                     \
    float x0 = __uint_as_float((xu0) << 16);                               \
    float x1 = __uint_as_float((xu0) & 0xffff0000u);                       \
    float x2 = __uint_as_float((xu1) << 16);                               \
    float x3 = __uint_as_float((xu1) & 0xffff0000u);                       \
    float rv0 = fmaf(x0, (r4).x, fmaf((b4).x, INV2PI, t2));                \
    AC0 = fmaf(__builtin_amdgcn_cosf(rv0), (a4).x, AC0);                   \
    AS0 = fmaf(__builtin_amdgcn_sinf(rv0), (s4).x, AS0);                   \
    float rv1 = fmaf(x1, (r4).y, fmaf((b4).y, INV2PI, t2));                \
    AC1 = fmaf(__builtin_amdgcn_cosf(rv1), (a4).y, AC1);                   \
    AS1 = fmaf(__builtin_amdgcn_sinf(rv1), (s4).y, AS1);                   \
    float rv2 = fmaf(x2, (r4).z, fmaf((b4).z, INV2PI, t2));                \
    AC0 = fmaf(__builtin_amdgcn_cosf(rv2), (a4).z, AC0);                   \
    AS0 = fmaf(__builtin_amdgcn_sinf(rv2), (s4).z, AS0);                   \
    float rv3 = fmaf(x3, (r4).w, fmaf((b4).w, INV2PI, t2));                \
    AC1 = fmaf(__builtin_amdgcn_cosf(rv3), (a4).w, AC1);                   \
    AS1 = fmaf(__builtin_amdgcn_sinf(rv3), (s4).w, AS1);                   \
  } while (0)

__global__ __launch_bounds__(512) void k2_resonant(
    const uint32_t* __restrict__ xcp, const float* __restrict__ rinv,
    const float* __restrict__ Bp, const float* __restrict__ ac,
    const float* __restrict__ as_, const float* __restrict__ tin,
    float* __restrict__ csP, float* __restrict__ ssP)
{
  __shared__ __align__(16) uint32_t xlds[64][64];    // 16 KB: d-eighth of xcp
  __shared__ __align__(16) float plds[2][8][4][64];  // 16 KB: params, 2 chunks
  int wave = __builtin_amdgcn_readfirstlane((int)(threadIdx.x >> 6));
  int lane = threadIdx.x & 63;
  int bid = blockIdx.x;
  int q = bid & 7;                 // d-eighth
  int n = (bid >> 3) * 8 + wave;   // neuron
  float t2 = tin[lane] * INV2PI;

  // ---- stage xcp eighth-slice (64 pair-rows): 16 x 1KB calls; wave w does 2
  const char* xsrc = (const char*)(xcp + (size_t)q * 64 * 64);
  char* xdst = (char*)&xlds[0][0];
#pragma unroll
  for (int r = 0; r < 2; ++r) {
    int j = wave * 2 + r;  // call j stages rows 4j..4j+3
    __builtin_amdgcn_global_load_lds(
        (const __attribute__((address_space(1))) void*)(xsrc + j * 1024 + lane * 16),
        (__attribute__((address_space(3))) void*)(xdst + j * 1024), 16, 0, 0);
  }

  // ---- stage BOTH param chunks for this wave: lane l -> array (l>>4),
  // elements (l&15)*4
  int g = lane >> 4;
  const float* ab = (g == 0) ? rinv : (g == 1) ? Bp : (g == 2) ? ac : as_;
  const float* gp = ab + (size_t)n * 1024 + (size_t)q * 128 + (lane & 15) * 4;
#pragma unroll
  for (int c = 0; c < 2; ++c) {
    __builtin_amdgcn_global_load_lds(
        (const __attribute__((address_space(1))) void*)(gp + c * 64),
        (__attribute__((address_space(3))) void*)&plds[c][wave][0][0], 16, 0, 0);
  }

  __syncthreads();  // drains vmcnt: all LDS staging complete

  float ac0 = 0.f, as0 = 0.f, ac1 = 0.f, as1 = 0.f;
  float ac2 = 0.f, as2 = 0.f, ac3 = 0.f, as3 = 0.f;

  {
    const float4* pr = (const float4*)&plds[0][wave][0][0];  // [4][16]
#pragma unroll
    for (int i = 0; i < 16; ++i) {
      uint32_t xu0 = xlds[2 * i][lane];
      uint32_t xu1 = xlds[2 * i + 1][lane];
      float4 r4 = pr[i];
      float4 b4 = pr[16 + i];
      float4 a4 = pr[32 + i];
      float4 s4 = pr[48 + i];
      K2_STEP(r4, b4, a4, s4, xu0, xu1, ac0, as0, ac1, as1);
    }
  }
  {
    const float4* pr = (const float4*)&plds[1][wave][0][0];
#pragma unroll
    for (int i = 0; i < 16; ++i) {
      uint32_t xu0 = xlds[32 + 2 * i][lane];
      uint32_t xu1 = xlds[32 + 2 * i + 1][lane];
      float4 r4 = pr[i];
      float4 b4 = pr[16 + i];
      float4 a4 = pr[32 + i];
      float4 s4 = pr[48 + i];
      K2_STEP(r4, b4, a4, s4, xu0, xu1, ac2, as2, ac3, as3);
    }
  }

  size_t o = ((size_t)q * 2048 + n) * 64 + lane;
  csP[o] = (ac0 + ac1) + (ac2 + ac3);
  ssP[o] = (as0 + as1) + (as2 + as3);
}

// ---------------- K2b: sum the 8 d-eighth partials, pack to bf16 pairs ----
// csB/ssB[npair][b] u32 = bf16(n even) | bf16(n odd)<<16.
__global__ __launch_bounds__(256) void k2b_reduce(
    const float* __restrict__ csP, const float* __restrict__ ssP,
    uint32_t* __restrict__ csB, uint32_t* __restrict__ ssB)
{
  int i = blockIdx.x * 256 + threadIdx.x;  // 0..65535 (npair, b)
  int np = i >> 6, b = i & 63;
  int n0 = 2 * np;
  float c0 = 0.f, c1 = 0.f, s0 = 0.f, s1 = 0.f;
#pragma unroll
  for (int j = 0; j < 8; ++j) {
    size_t base = ((size_t)j * 2048 + n0) * 64 + b;
    c0 += csP[base];
    c1 += csP[base + 64];
    s0 += ssP[base];
    s1 += ssP[base + 64];
  }
  csB[i] = bf16r(c0) | (bf16r(c1) << 16);
  ssB[i] = bf16r(s0) | (bf16r(s1) << 16);
}

// ---------------- K3: output GEMMs + SiLU (packed src, batched s_loads) ----
// out[sel][b][d] = silu(sum_n src[n][b] * w[d][n]); src packed bf16 pairs
// (halves L2 traffic + loads); 16-n batches of 4-row x 64 B s_loads.
__global__ __launch_bounds__(512) void k3_out(
    const uint32_t* __restrict__ csB, const uint32_t* __restrict__ ssB,
    const float* __restrict__ wr, const float* __restrict__ wi,
    float* __restrict__ out)
{
  __shared__ float part[8][4][65];
  int bid = blockIdx.x;
  int sel = bid >> 8;
  int d0 = (bid & 255) * 4;
  int wave = __builtin_amdgcn_readfirstlane((int)(threadIdx.x >> 6));
  int lane = threadIdx.x & 63;
  const uint32_t* src2 = sel ? ssB : csB;
  const float* wt = sel ? wi : wr;
  float acc[4] = {0.f, 0.f, 0.f, 0.f};
  int n0 = wave * 256;
  for (int i = 0; i < 16; ++i) {  // 16 n per batch
    int n = n0 + i * 16;
    float4 w[4][4];
#pragma unroll
    for (int r = 0; r < 4; ++r)
#pragma unroll
      for (int j = 0; j < 4; ++j)
        w[r][j] = *(const float4*)(wt + (size_t)(d0 + r) * 2048 + n + 4 * j);
    uint32_t xu[8];
#pragma unroll
    for (int j = 0; j < 8; ++j)
      xu[j] = src2[(size_t)((n >> 1) + j) * 64 + lane];
#pragma unroll
    for (int j = 0; j < 8; ++j) {  // 2 n per j
      float cv0 = __uint_as_float(xu[j] << 16);         // even n
      float cv1 = __uint_as_float(xu[j] & 0xffff0000u); // odd n
      const int q4 = j >> 1;
      if ((j & 1) == 0) {
#pragma unroll
        for (int r = 0; r < 4; ++r) {
          acc[r] = fmaf(cv0, w[r][q4].x, acc[r]);
          acc[r] = fmaf(cv1, w[r][q4].y, acc[r]);
        }
      } else {
#pragma unroll
        for (int r = 0; r < 4; ++r) {
          acc[r] = fmaf(cv0, w[r][q4].z, acc[r]);
          acc[r] = fmaf(cv1, w[r][q4].w, acc[r]);
        }
      }
    }
  }
#pragma unroll
  for (int r = 0; r < 4; ++r) part[wave][r][lane] = acc[r];
  __syncthreads();
  int t = threadIdx.x;
  if (t < 256) {
    int b = t >> 2, j = t & 3;
    float s = 0.f;
#pragma unroll
    for (int w = 0; w < 8; ++w) s += part[w][j][b];
    float y = s / (1.0f + __expf(-s));  // silu
    out[(size_t)sel * 65536 + (size_t)b * 1024 + d0 + j] = y;
  }
}

extern "C" void kernel_launch(void* const* d_in, const int* in_sizes, int n_in,
                              void* d_out, int out_size, void* d_ws, size_t ws_size,
                              hipStream_t stream) {
  const float* xr  = (const float*)d_in[0];
  const float* xi  = (const float*)d_in[1];
  const float* t   = (const float*)d_in[2];
  const float* icw = (const float*)d_in[3];
  const float* icb = (const float*)d_in[4];
  const float* W   = (const float*)d_in[5];
  const float* Bp  = (const float*)d_in[6];
  const float* ac  = (const float*)d_in[7];
  const float* as_ = (const float*)d_in[8];
  const float* wr  = (const float*)d_in[9];
  const float* wi  = (const float*)d_in[10];
  // sin/cos tables (d_in[11], d_in[12]) replaced by hw v_sin/v_cos (err ~1e-6)

  float* ws = (float*)d_ws;
  float* rinv   = ws;                          // 2M f32
  float* xcombP = ws + 2097152;                // 131072
  uint32_t* xcp = (uint32_t*)(ws + 2228224);   // 32768 u32
  float* csP    = ws + 2260992;                // 1048576 (8 x 2048 x 64)
  float* ssP    = ws + 3309568;                // 1048576
  uint32_t* csB = (uint32_t*)(ws + 4358144);   // 65536 u32
  uint32_t* ssB = (uint32_t*)(ws + 4423680);   // 65536 u32
  float* out = (float*)d_out;

  k0_prep<<<dim3(288), dim3(256), 0, stream>>>(xr, xi, W, xcombP, rinv);
  k1_collapse<<<dim3(256), dim3(512), 0, stream>>>(xcombP, icw, icb, xcp);
  k2_resonant<<<dim3(2048), dim3(512), 0, stream>>>(xcp, rinv, Bp, ac, as_, t, csP, ssP);
  k2b_reduce<<<dim3(256), dim3(256), 0, stream>>>(csP, ssP, csB, ssB);
  k3_out<<<dim3(512), dim3(512), 0, stream>>>(csB, ssB, wr, wi, out);
}

// Round 10
// 75.721 us; speedup vs baseline: 1.2304x; 1.2304x over previous
//
#include <hip/hip_runtime.h>
#include <stdint.h>

// Sizes fixed by the problem.
#define DM 1024   // D_MODEL
#define NN 2048   // NUM_NEURONS
#define BB 64     // batch (== wavefront size!)

static constexpr float INV2PI = 0.15915494309189535f;

__device__ __forceinline__ uint32_t bf16r(float x) {
  uint32_t b = __float_as_uint(x);
  b += 0x7fffu + ((b >> 16) & 1u);
  return b >> 16;
}

// ---------------- K0: prep ----------------
// blocks [0,32):   xcombP tiles (x_real/x_imag [64][1024] -> [1024 kpair][64 b] float2)
// blocks [32,288): rinv = 1/(1+|W|) elementwise (2M f32)
__global__ __launch_bounds__(256) void k0_prep(
    const float* __restrict__ xr, const float* __restrict__ xi,
    const float* __restrict__ W,
    float* __restrict__ xcombP, float* __restrict__ rinv)
{
  __shared__ float tile[64][65];
  int bid = blockIdx.x;
  int t = threadIdx.x;
  if (bid < 32) {
    int j = bid;  // k-tile of 64 over concatenated 2048
    int k0 = j * 64;
    const float* src = (k0 < 1024) ? xr : xi;
    int koff = k0 & 1023;
    int c = t & 63, rl = t >> 6;
#pragma unroll
    for (int i = 0; i < 16; ++i) {
      int b = rl * 16 + i;
      tile[b][c] = src[b * 1024 + koff + c];  // tile[b][k_local]
    }
    __syncthreads();
    float2* out2 = (float2*)xcombP;  // [1024 kpair][64 b]
    int bl = t & 63, kp = t >> 6;    // kp 0..3
#pragma unroll
    for (int i = 0; i < 8; ++i) {
      int kl = (kp * 8 + i) * 2;
      float2 v = make_float2(tile[bl][kl], tile[bl][kl + 1]);
      out2[(size_t)((k0 + kl) >> 1) * 64 + bl] = v;
    }
  } else {
    int j = bid - 32;  // 0..255, 2048 float4 each over 524288 total
    const float4* W4 = (const float4*)W;
    float4* R4 = (float4*)rinv;
    int base = j * 2048 + t;
#pragma unroll
    for (int i = 0; i < 8; ++i) {
      int idx = base + i * 256;
      float4 w = W4[idx];
      float4 r;
      r.x = 1.0f / (1.0f + fabsf(w.x));
      r.y = 1.0f / (1.0f + fabsf(w.y));
      r.z = 1.0f / (1.0f + fabsf(w.z));
      r.w = 1.0f / (1.0f + fabsf(w.w));
      R4[idx] = r;
    }
  }
}

// ---------------- K1: x_collapsed (d-tile 4, 16 waves, k-split 16) ---------
// xc[b,d] = sum_k xcomb[b,k]*ic_w[d,k] + ic_b[d]; store packed bf16 pairs of
// xc*INV2PI as xcp[d/2][b]. 1024 thr: 16 waves each own 128 k -> 16 waves/CU.
__global__ __launch_bounds__(1024) void k1_collapse(
    const float* __restrict__ xcombP, const float* __restrict__ icw,
    const float* __restrict__ icb, uint32_t* __restrict__ xcp)
{
  __shared__ float part[16][4][64];
  int d0 = blockIdx.x * 4;
  int wave = __builtin_amdgcn_readfirstlane((int)(threadIdx.x >> 6));
  int lane = threadIdx.x & 63;
  const float2* P2 = (const float2*)xcombP;
  float acc[4] = {0.f, 0.f, 0.f, 0.f};
  int kbase = wave * 128;
  for (int kk = 0; kk < 128; kk += 4) {
    int k = kbase + kk;
    float2 xa = P2[(size_t)(k >> 1) * 64 + lane];        // k, k+1
    float2 xb = P2[(size_t)((k >> 1) + 1) * 64 + lane];  // k+2, k+3
#pragma unroll
    for (int r = 0; r < 4; ++r) {
      float4 w = *(const float4*)(icw + (size_t)(d0 + r) * 2048 + k);  // s_load
      acc[r] = fmaf(w.x, xa.x, acc[r]);
      acc[r] = fmaf(w.y, xa.y, acc[r]);
      acc[r] = fmaf(w.z, xb.x, acc[r]);
      acc[r] = fmaf(w.w, xb.y, acc[r]);
    }
  }
#pragma unroll
  for (int r = 0; r < 4; ++r) part[wave][r][lane] = acc[r];
  __syncthreads();
  int t = threadIdx.x;
  if (t < 128) {
    int pj = t >> 6;  // 0..1 (d-pair within tile)
    int b = t & 63;
    float s0 = 0.f, s1 = 0.f;
#pragma unroll
    for (int w = 0; w < 16; ++w) {
      s0 += part[w][2 * pj][b];
      s1 += part[w][2 * pj + 1][b];
    }
    float x0 = (s0 + icb[d0 + 2 * pj]) * INV2PI;
    float x1 = (s1 + icb[d0 + 2 * pj + 1]) * INV2PI;
    uint32_t u = bf16r(x0) | (bf16r(x1) << 16);
    xcp[(size_t)((d0 >> 1) + pj) * 64 + b] = u;
  }
}

// ---------------- K2: the resonant map-reduce (R6-proven form, verbatim) ---
// lane = b. wave owns (n, d-eighth q). 2048 blocks x 8 waves. LDS = 32 KB.
// ALL staging issued before ONE barrier; inner loop pure LDS+VALU+trans.
#define K2_STEP(r4, b4, a4, s4, xu0, xu1)                                 \
  do {                                                                     \
    float x0 = __uint_as_float((xu0) << 16);                               \
    float x1 = __uint_as_float((xu0) & 0xffff0000u);                       \
    float x2 = __uint_as_float((xu1) << 16);                               \
    float x3 = __uint_as_float((xu1) & 0xffff0000u);                       \
    float rv0 = fmaf(x0, (r4).x, fmaf((b4).x, INV2PI, t2));                \
    accc0 = fmaf(__builtin_amdgcn_cosf(rv0), (a4).x, accc0);               \
    accs0 = fmaf(__builtin_amdgcn_sinf(rv0), (s4).x, accs0);               \
    float rv1 = fmaf(x1, (r4).y, fmaf((b4).y, INV2PI, t2));                \
    accc1 = fmaf(__builtin_amdgcn_cosf(rv1), (a4).y, accc1);               \
    accs1 = fmaf(__builtin_amdgcn_sinf(rv1), (s4).y, accs1);               \
    float rv2 = fmaf(x2, (r4).z, fmaf((b4).z, INV2PI, t2));                \
    accc0 = fmaf(__builtin_amdgcn_cosf(rv2), (a4).z, accc0);               \
    accs0 = fmaf(__builtin_amdgcn_sinf(rv2), (s4).z, accs0);               \
    float rv3 = fmaf(x3, (r4).w, fmaf((b4).w, INV2PI, t2));                \
    accc1 = fmaf(__builtin_amdgcn_cosf(rv3), (a4).w, accc1);               \
    accs1 = fmaf(__builtin_amdgcn_sinf(rv3), (s4).w, accs1);               \
  } while (0)

__global__ __launch_bounds__(512) void k2_resonant(
    const uint32_t* __restrict__ xcp, const float* __restrict__ rinv,
    const float* __restrict__ Bp, const float* __restrict__ ac,
    const float* __restrict__ as_, const float* __restrict__ tin,
    float* __restrict__ csP, float* __restrict__ ssP)
{
  __shared__ __align__(16) uint32_t xlds[64][64];    // 16 KB: d-eighth of xcp
  __shared__ __align__(16) float plds[2][8][4][64];  // 16 KB: params, 2 chunks
  int wave = __builtin_amdgcn_readfirstlane((int)(threadIdx.x >> 6));
  int lane = threadIdx.x & 63;
  int bid = blockIdx.x;
  int q = bid & 7;                 // d-eighth
  int n = (bid >> 3) * 8 + wave;   // neuron
  float t2 = tin[lane] * INV2PI;

  // ---- stage xcp eighth-slice (64 pair-rows): 16 x 1KB calls; wave w does 2
  const char* xsrc = (const char*)(xcp + (size_t)q * 64 * 64);
  char* xdst = (char*)&xlds[0][0];
#pragma unroll
  for (int r = 0; r < 2; ++r) {
    int j = wave * 2 + r;  // call j stages rows 4j..4j+3
    __builtin_amdgcn_global_load_lds(
        (const __attribute__((address_space(1))) void*)(xsrc + j * 1024 + lane * 16),
        (__attribute__((address_space(3))) void*)(xdst + j * 1024), 16, 0, 0);
  }

  // ---- stage BOTH param chunks for this wave: lane l -> array (l>>4),
  // elements (l&15)*4
  int g = lane >> 4;
  const float* ab = (g == 0) ? rinv : (g == 1) ? Bp : (g == 2) ? ac : as_;
  const float* gp = ab + (size_t)n * 1024 + (size_t)q * 128 + (lane & 15) * 4;
#pragma unroll
  for (int c = 0; c < 2; ++c) {
    __builtin_amdgcn_global_load_lds(
        (const __attribute__((address_space(1))) void*)(gp + c * 64),
        (__attribute__((address_space(3))) void*)&plds[c][wave][0][0], 16, 0, 0);
  }

  __syncthreads();  // drains vmcnt: all LDS staging complete

  float accc0 = 0.f, accs0 = 0.f, accc1 = 0.f, accs1 = 0.f;

#pragma unroll
  for (int c = 0; c < 2; ++c) {
    const float4* pr = (const float4*)&plds[c][wave][0][0];  // [4][16]
#pragma unroll 4
    for (int i = 0; i < 16; ++i) {
      int ga = c * 16 + i;
      uint32_t xu0 = xlds[2 * ga][lane];
      uint32_t xu1 = xlds[2 * ga + 1][lane];
      float4 r4 = pr[i];
      float4 b4 = pr[16 + i];
      float4 a4 = pr[32 + i];
      float4 s4 = pr[48 + i];
      K2_STEP(r4, b4, a4, s4, xu0, xu1);
    }
  }

  size_t o = ((size_t)q * 2048 + n) * 64 + lane;
  csP[o] = accc0 + accc1;
  ssP[o] = accs0 + accs1;
}

// ---------------- K2b: sum the 8 d-eighth partials, pack to bf16 pairs ----
// csB/ssB[npair][b] u32 = bf16(n even) | bf16(n odd)<<16.
__global__ __launch_bounds__(256) void k2b_reduce(
    const float* __restrict__ csP, const float* __restrict__ ssP,
    uint32_t* __restrict__ csB, uint32_t* __restrict__ ssB)
{
  int i = blockIdx.x * 256 + threadIdx.x;  // 0..65535 (npair, b)
  int np = i >> 6, b = i & 63;
  int n0 = 2 * np;
  float c0 = 0.f, c1 = 0.f, s0 = 0.f, s1 = 0.f;
#pragma unroll
  for (int j = 0; j < 8; ++j) {
    size_t base = ((size_t)j * 2048 + n0) * 64 + b;
    c0 += csP[base];
    c1 += csP[base + 64];
    s0 += ssP[base];
    s1 += ssP[base + 64];
  }
  csB[i] = bf16r(c0) | (bf16r(c1) << 16);
  ssB[i] = bf16r(s0) | (bf16r(s1) << 16);
}

// ---------------- K3: output GEMMs + SiLU (packed src, 16 waves) -----------
// out[sel][b][d] = silu(sum_n src[n][b] * w[d][n]); 1024 thr: 16 waves each
// own 128 n -> 32 waves/CU at 2 blocks/CU. src packed bf16 pairs.
__global__ __launch_bounds__(1024) void k3_out(
    const uint32_t* __restrict__ csB, const uint32_t* __restrict__ ssB,
    const float* __restrict__ wr, const float* __restrict__ wi,
    float* __restrict__ out)
{
  __shared__ float part[16][4][65];
  int bid = blockIdx.x;
  int sel = bid >> 8;
  int d0 = (bid & 255) * 4;
  int wave = __builtin_amdgcn_readfirstlane((int)(threadIdx.x >> 6));
  int lane = threadIdx.x & 63;
  const uint32_t* src2 = sel ? ssB : csB;
  const float* wt = sel ? wi : wr;
  float acc[4] = {0.f, 0.f, 0.f, 0.f};
  int n0 = wave * 128;
  for (int i = 0; i < 32; ++i) {  // 4 n per iter
    int n = n0 + i * 4;
    uint32_t xu0 = src2[(size_t)(n >> 1) * 64 + lane];
    uint32_t xu1 = src2[(size_t)((n >> 1) + 1) * 64 + lane];
    float cv0 = __uint_as_float(xu0 << 16);
    float cv1 = __uint_as_float(xu0 & 0xffff0000u);
    float cv2 = __uint_as_float(xu1 << 16);
    float cv3 = __uint_as_float(xu1 & 0xffff0000u);
#pragma unroll
    for (int r = 0; r < 4; ++r) {
      float4 wv = *(const float4*)(wt + (size_t)(d0 + r) * 2048 + n);  // s_load
      acc[r] = fmaf(cv0, wv.x, acc[r]);
      acc[r] = fmaf(cv1, wv.y, acc[r]);
      acc[r] = fmaf(cv2, wv.z, acc[r]);
      acc[r] = fmaf(cv3, wv.w, acc[r]);
    }
  }
#pragma unroll
  for (int r = 0; r < 4; ++r) part[wave][r][lane] = acc[r];
  __syncthreads();
  int t = threadIdx.x;
  if (t < 256) {
    int b = t >> 2, j = t & 3;
    float s = 0.f;
#pragma unroll
    for (int w = 0; w < 16; ++w) s += part[w][j][b];
    float y = s / (1.0f + __expf(-s));  // silu
    out[(size_t)sel * 65536 + (size_t)b * 1024 + d0 + j] = y;
  }
}

extern "C" void kernel_launch(void* const* d_in, const int* in_sizes, int n_in,
                              void* d_out, int out_size, void* d_ws, size_t ws_size,
                              hipStream_t stream) {
  const float* xr  = (const float*)d_in[0];
  const float* xi  = (const float*)d_in[1];
  const float* t   = (const float*)d_in[2];
  const float* icw = (const float*)d_in[3];
  const float* icb = (const float*)d_in[4];
  const float* W   = (const float*)d_in[5];
  const float* Bp  = (const float*)d_in[6];
  const float* ac  = (const float*)d_in[7];
  const float* as_ = (const float*)d_in[8];
  const float* wr  = (const float*)d_in[9];
  const float* wi  = (const float*)d_in[10];
  // sin/cos tables (d_in[11], d_in[12]) replaced by hw v_sin/v_cos (err ~1e-6)

  float* ws = (float*)d_ws;
  float* rinv   = ws;                          // 2M f32
  float* xcombP = ws + 2097152;                // 131072
  uint32_t* xcp = (uint32_t*)(ws + 2228224);   // 32768 u32
  float* csP    = ws + 2260992;                // 1048576 (8 x 2048 x 64)
  float* ssP    = ws + 3309568;                // 1048576
  uint32_t* csB = (uint32_t*)(ws + 4358144);   // 65536 u32
  uint32_t* ssB = (uint32_t*)(ws + 4423680);   // 65536 u32
  float* out = (float*)d_out;

  k0_prep<<<dim3(288), dim3(256), 0, stream>>>(xr, xi, W, xcombP, rinv);
  k1_collapse<<<dim3(256), dim3(1024), 0, stream>>>(xcombP, icw, icb, xcp);
  k2_resonant<<<dim3(2048), dim3(512), 0, stream>>>(xcp, rinv, Bp, ac, as_, t, csP, ssP);
  k2b_reduce<<<dim3(256), dim3(256), 0, stream>>>(csP, ssP, csB, ssB);
  k3_out<<<dim3(512), dim3(1024), 0, stream>>>(csB, ssB, wr, wi, out);
}